// Round 13
// baseline (2285.594 us; speedup 1.0000x reference)
//
#include <hip/hip_runtime.h>
#include <math.h>

#define T 128
#define B 128
#define H 256
#define I 256
#define G4 1024  // 4*H
#define NB 2     // batch elements per block

typedef unsigned short u16;
typedef unsigned int u32;
typedef _Float16 half_t;
typedef _Float16 half2_t __attribute__((ext_vector_type(2)));

#if defined(__has_builtin)
#if __has_builtin(__builtin_amdgcn_fdot2)
#define HAS_FDOT2 1
#endif
#endif

__device__ __forceinline__ float fdot2(half2_t a, half2_t b, float c) {
#ifdef HAS_FDOT2
    return __builtin_amdgcn_fdot2(a, b, c, false);
#else
    return fmaf((float)a.x, (float)b.x, fmaf((float)a.y, (float)b.y, c));
#endif
}
__device__ __forceinline__ half2_t h2cast(u32 u) { return __builtin_bit_cast(half2_t, u); }

__device__ __forceinline__ float sigmoid_fast(float x) {
    return 1.0f / (1.0f + __expf(-x));
}
__device__ __forceinline__ float tanh_fast(float x) {
    x = fminf(fmaxf(x, -15.f), 15.f);
    const float e = __expf(2.0f * x);
    return (e - 1.0f) / (e + 1.0f);
}

// LDS-only barrier (validated rounds 9-12: bit-identical absmax, neutral cost).
#define BARL() do {                                        \
    asm volatile("s_waitcnt lgkmcnt(0)" ::: "memory");     \
    __builtin_amdgcn_s_barrier();                          \
} while (0)

// ---------------- weight repack (one-shot, fp16 k4-packed, k-major == coalesced) ----------------
// WhH4[k4][o] = uint2{ h2(Whh[o][4k4],Whh[o][4k4+1]), h2(Whh[o][4k4+2],Whh[o][4k4+3]) }
// k4 < 64, o < 1024. Lane-consecutive o -> 8B/lane coalesced stream.
__global__ void pack_whH4(const float* __restrict__ Whh, uint2* __restrict__ WhH4) {
    const int k4 = blockIdx.x;      // 0..63
    const int o  = threadIdx.x;     // 0..1023
    half2_t a, b;
    a.x = (half_t)Whh[(size_t)o * H + 4 * k4];
    a.y = (half_t)Whh[(size_t)o * H + 4 * k4 + 1];
    b.x = (half_t)Whh[(size_t)o * H + 4 * k4 + 2];
    b.y = (half_t)Whh[(size_t)o * H + 4 * k4 + 3];
    WhH4[(size_t)k4 * G4 + o] = make_uint2(__builtin_bit_cast(u32, a), __builtin_bit_cast(u32, b));
}
// WaH4[k4][j], k4 < 128 (2H=512 k), j < 256
__global__ void pack_waH4(const float* __restrict__ Wa, uint2* __restrict__ WaH4) {
    const int k4 = blockIdx.x;      // 0..127
    const int j  = threadIdx.x;     // 0..255
    half2_t a, b;
    a.x = (half_t)Wa[(size_t)j * (2 * H) + 4 * k4];
    a.y = (half_t)Wa[(size_t)j * (2 * H) + 4 * k4 + 1];
    b.x = (half_t)Wa[(size_t)j * (2 * H) + 4 * k4 + 2];
    b.y = (half_t)Wa[(size_t)j * (2 * H) + 4 * k4 + 3];
    WaH4[(size_t)k4 * H + j] = make_uint2(__builtin_bit_cast(u32, a), __builtin_bit_cast(u32, b));
}

// ---------------- G = embs @ Wih^T + bih + bhh ----------------
__global__ __launch_bounds__(256) void gemm_g(const float* __restrict__ A,
                                              const float* __restrict__ W,
                                              const float* __restrict__ bih,
                                              const float* __restrict__ bhh,
                                              float* __restrict__ G) {
    __shared__ __align__(16) float As[64][68];
    __shared__ __align__(16) float Ws[64][68];
    const int m0 = blockIdx.x * 64;
    const int n0 = blockIdx.y * 64;
    const int tid = threadIdx.x;
    const int ty = tid >> 4, tx = tid & 15;
    const int rr = tid >> 4;
    const int kr = tid & 15;

    float acc[4][4] = {};
    for (int k0 = 0; k0 < I; k0 += 64) {
#pragma unroll
        for (int i = 0; i < 4; ++i) {
            const int r = rr + 16 * i;
            const float4 av = *(const float4*)&A[(size_t)(m0 + r) * I + k0 + kr * 4];
            const float4 wv = *(const float4*)&W[(size_t)(n0 + r) * I + k0 + kr * 4];
            As[kr * 4 + 0][r] = av.x; As[kr * 4 + 1][r] = av.y;
            As[kr * 4 + 2][r] = av.z; As[kr * 4 + 3][r] = av.w;
            Ws[kr * 4 + 0][r] = wv.x; Ws[kr * 4 + 1][r] = wv.y;
            Ws[kr * 4 + 2][r] = wv.z; Ws[kr * 4 + 3][r] = wv.w;
        }
        __syncthreads();
#pragma unroll 8
        for (int kk = 0; kk < 64; ++kk) {
            const float4 a4 = *(const float4*)&As[kk][ty * 4];
            const float4 w4 = *(const float4*)&Ws[kk][tx * 4];
            const float a[4] = {a4.x, a4.y, a4.z, a4.w};
            const float w[4] = {w4.x, w4.y, w4.z, w4.w};
#pragma unroll
            for (int i = 0; i < 4; ++i)
#pragma unroll
                for (int jj = 0; jj < 4; ++jj)
                    acc[i][jj] = fmaf(a[i], w[jj], acc[i][jj]);
        }
        __syncthreads();
    }
    const int n = n0 + tx * 4;
    const float4 bi = *(const float4*)&bih[n];
    const float4 bh = *(const float4*)&bhh[n];
    const float4 bb = make_float4(bi.x + bh.x, bi.y + bh.y, bi.z + bh.z, bi.w + bh.w);
#pragma unroll
    for (int i = 0; i < 4; ++i) {
        const int m = m0 + ty * 4 + i;
        float4 o = make_float4(acc[i][0] + bb.x, acc[i][1] + bb.y,
                               acc[i][2] + bb.z, acc[i][3] + bb.w);
        *(float4*)&G[(size_t)m * G4 + n] = o;
    }
}

// ---------------- recurrent attention-LSTM: NB=2, k4 fdot2 GEMVs, LDS-only barriers ----------------
// LDS: hid 131072 + sc 1024 + hH 1024 + hcI 2048 + hinI 1024 + red 8192 + gate 8192
//      = 152576 B <= 163840 (1 block/CU, 16 waves)
__global__ __launch_bounds__(1024, 4) void alstm8(
    const int* __restrict__ lens,
    const float* __restrict__ G,       // [T*B][4H]
    const uint2* __restrict__ WhH4,    // [64][1024] k4-major
    const uint2* __restrict__ WaH4,    // [128][256]  k4-major
    const float* __restrict__ ba,
    float* __restrict__ out)           // hs | h_fin | c_fin
{
    __shared__ __align__(16) half_t hid_s[NB][T][H];   // fp16 history, 128 KB
    __shared__ __align__(16) float  sc_s[NB][T];
    __shared__ __align__(16) half_t hH_s[NB][H];       // h (for scores)
    __shared__ __align__(16) half_t hcI_s[4 * 256];    // [h|ctx], batch-interleaved k-pairs
    __shared__ __align__(16) half_t hinI_s[4 * 128];   // hin, batch-interleaved k-pairs
    __shared__ __align__(16) float  red_s[2048];       // phase-reuse reduce buffer
    __shared__ __align__(16) float  gate_s[NB][G4];    // prefetched G rows

    const int b0 = blockIdx.x * NB;
    const int tid = threadIdx.x;
    const int lane = tid & 63;
    const int wave = tid >> 6;        // 0..15
    const int sb = wave >> 3;         // scores batch
    const int stp0 = wave & 7;        // scores t'-stride id
    const int cb = tid >> 9;          // ctx batch
    const int ck4 = (tid >> 7) & 3;   // ctx 4-way t-split
    const int cjp = tid & 127;        // ctx feature pair
    const int ako = tid >> 8;         // Wa k4-chunk 0..3 (32 k4 each)
    const int aj = tid & 255;         // Wa output j
    const int eb = tid >> 8;          // cell batch (valid under tid<512)
    const int ej = tid & 255;         // cell feature

    const int len0 = lens[b0], len1 = lens[b0 + 1];
    float c_reg = 0.f;
    float* hfin = out + (size_t)T * B * H;
    float* cfin = hfin + (size_t)B * H;
    if (tid < 512) hH_s[eb][ej] = (half_t)0.f;

    const uint2* wap = &WaH4[(size_t)(ako * 32) * H + aj];  // 32 iters, stride H uint2
    const uint2* whp = &WhH4[tid];                          // 64 iters, stride G4 uint2
    const uint4* hinv4 = (const uint4*)hinI_s;              // [k4] -> 2 pairs x 2 batches
    const uint4* hcIv4 = (const uint4*)hcI_s;
    float2* red2 = (float2*)red_s;
    BARL();

    for (int t = 0; t < T; ++t) {
        // G-row loads issue here; consumed at the gate stash (P2).
        const float gA = G[((size_t)t * B + b0) * G4 + tid];
        const float gB = G[((size_t)t * B + b0 + 1) * G4 + tid];

        if (t > 0) {
            // ---- P0: scores (8 waves per batch, t' strided) ----
            {
                const half2_t h2a = h2cast(*(const u32*)&hH_s[sb][lane * 4]);
                const half2_t h2b = h2cast(*(const u32*)&hH_s[sb][lane * 4 + 2]);
                for (int tp = stp0; tp < t; tp += 8) {
                    const uint2 hv = *(const uint2*)&hid_s[sb][tp][lane * 4];
                    float d = fdot2(h2cast(hv.x), h2a, fdot2(h2cast(hv.y), h2b, 0.f));
#pragma unroll
                    for (int off = 32; off; off >>= 1) d += __shfl_xor(d, off);
                    if (lane == 0) sc_s[sb][tp] = d;
                }
            }
            BARL();  // A
            // ---- P1: softmax (wave 0 -> batch 0, wave 8 -> batch 1) ----
            if (stp0 == 0) {
                const float v0 = (lane < t) ? sc_s[sb][lane] : -3.0e38f;
                const float v1 = (lane + 64 < t) ? sc_s[sb][lane + 64] : -3.0e38f;
                float m = fmaxf(v0, v1);
#pragma unroll
                for (int off = 32; off; off >>= 1) m = fmaxf(m, __shfl_xor(m, off));
                const float e0 = (lane < t) ? __expf(v0 - m) : 0.f;
                const float e1 = (lane + 64 < t) ? __expf(v1 - m) : 0.f;
                float s = e0 + e1;
#pragma unroll
                for (int off = 32; off; off >>= 1) s += __shfl_xor(s, off);
                const float inv = 1.f / s;
                if (lane < t) sc_s[sb][lane] = e0 * inv;
                if (lane + 64 < t) sc_s[sb][lane + 64] = e1 * inv;
            }
            BARL();  // B
            // ---- P2: ctx partials (feature-PAIR per thread, 4-way t-split) + G stash ----
            {
                float c0 = 0.f, c1 = 0.f;
                for (int tp = ck4; tp < t; tp += 4) {
                    const float w = sc_s[cb][tp];
                    const half2_t hv = h2cast(*(const u32*)&hid_s[cb][tp][cjp * 2]);
                    c0 = fmaf(w, (float)hv.x, c0);
                    c1 = fmaf(w, (float)hv.y, c1);
                }
                red2[cb * 512 + ck4 * 128 + cjp] = make_float2(c0, c1);
                gate_s[0][tid] = gA;
                gate_s[1][tid] = gB;
            }
            BARL();  // C
            // ---- P3a: ctx reduce (4 partials) -> hcI ctx half ----
            if (tid < 512) {
                const int p = ej >> 1, comp = ej & 1;
                const float ctxv = red_s[2 * (eb * 512 + 0 * 128 + p) + comp]
                                 + red_s[2 * (eb * 512 + 1 * 128 + p) + comp]
                                 + red_s[2 * (eb * 512 + 2 * 128 + p) + comp]
                                 + red_s[2 * (eb * 512 + 3 * 128 + p) + comp];
                hcI_s[512 + 4 * p + 2 * eb + comp] = (half_t)ctxv;
            }
            BARL();  // D
            // ---- P3: Wa GEMV (k4 stream: 1 load + 1 b128 + 4 fdot2 per 4k x 2 batches) ----
            {
                float a0 = 0.f, a1 = 0.f;
#pragma unroll 16
                for (int kk = 0; kk < 32; ++kk) {
                    const uint2 w = wap[(size_t)kk * H];
                    const uint4 hh = hcIv4[ako * 32 + kk];
                    a0 = fdot2(h2cast(w.x), h2cast(hh.x), a0);
                    a1 = fdot2(h2cast(w.x), h2cast(hh.y), a1);
                    a0 = fdot2(h2cast(w.y), h2cast(hh.z), a0);
                    a1 = fdot2(h2cast(w.y), h2cast(hh.w), a1);
                }
                red_s[ako * 512 + aj] = a0;
                red_s[ako * 512 + 256 + aj] = a1;
            }
            BARL();  // E
            // ---- P4: hin reduce + tanh ----
            if (tid < 512) {
                float a = ba[ej];
#pragma unroll
                for (int r = 0; r < 4; ++r) a += red_s[r * 512 + eb * 256 + ej];
                hinI_s[4 * (ej >> 1) + 2 * eb + (ej & 1)] = (half_t)tanh_fast(a);
            }
            BARL();  // F
            // ---- P5: Whh GEMV (one output o=tid, both batches, k4 stream) ----
            {
                float g0 = 0.f, g1 = 0.f;
#pragma unroll 16
                for (int k4 = 0; k4 < 64; ++k4) {
                    const uint2 w = whp[(size_t)k4 * G4];
                    const uint4 hh = hinv4[k4];
                    g0 = fdot2(h2cast(w.x), h2cast(hh.x), g0);
                    g1 = fdot2(h2cast(w.x), h2cast(hh.y), g1);
                    g0 = fdot2(h2cast(w.y), h2cast(hh.z), g0);
                    g1 = fdot2(h2cast(w.y), h2cast(hh.w), g1);
                }
                red_s[tid] = g0;
                red_s[1024 + tid] = g1;
            }
        } else {
            // t == 0: h_in = 0 -> recurrent contribution is exactly 0
            gate_s[0][tid] = gA;
            gate_s[1][tid] = gB;
            red_s[tid] = 0.f;
            red_s[1024 + tid] = 0.f;
        }
        BARL();  // G
        // ---- P6: gate sum + cell update (threads 0..511) ----
        if (tid < 512) {
            const int bg = b0 + eb;
            const float gi = gate_s[eb][ej]         + red_s[eb * 1024 + ej];
            const float gf = gate_s[eb][H + ej]     + red_s[eb * 1024 + H + ej];
            const float gg = gate_s[eb][2 * H + ej] + red_s[eb * 1024 + 2 * H + ej];
            const float go = gate_s[eb][3 * H + ej] + red_s[eb * 1024 + 3 * H + ej];
            const float ig = sigmoid_fast(gi);
            const float fg = sigmoid_fast(gf);
            const float gv = tanh_fast(gg);
            const float og = sigmoid_fast(go);
            c_reg = fmaf(fg, c_reg, ig * gv);
            const float h_new = og * tanh_fast(c_reg);
            const half_t hh = (half_t)h_new;
            hH_s[eb][ej] = hh;
            hid_s[eb][t][ej] = hh;
            hcI_s[4 * (ej >> 1) + 2 * eb + (ej & 1)] = hh;
            out[((size_t)t * B + bg) * H + ej] = h_new;
            const int lb = eb ? len1 : len0;
            if (t == lb - 1) {
                hfin[(size_t)bg * H + ej] = h_new;
                cfin[(size_t)bg * H + ej] = c_reg;
            }
        }
        BARL();  // H
    }
}

extern "C" void kernel_launch(void* const* d_in, const int* in_sizes, int n_in,
                              void* d_out, int out_size, void* d_ws, size_t ws_size,
                              hipStream_t stream) {
    const float* embs = (const float*)d_in[0];
    const int*   lens = (const int*)d_in[1];
    const float* Wih  = (const float*)d_in[2];
    const float* Whh  = (const float*)d_in[3];
    const float* bih  = (const float*)d_in[4];
    const float* bhh  = (const float*)d_in[5];
    const float* Wa   = (const float*)d_in[6];
    const float* ba   = (const float*)d_in[7];
    float* out = (float*)d_out;

    // ws layout: G fp32 [T*B][4H] (64 MB) | WhH4 uint2[64*1024] (512 KB) | WaH4 uint2[128*256] (256 KB)
    float* G     = (float*)d_ws;
    uint2* WhH4  = (uint2*)(G + (size_t)T * B * G4);
    uint2* WaH4  = WhH4 + (size_t)64 * G4;

    pack_whH4<<<64, G4, 0, stream>>>(Whh, WhH4);
    pack_waH4<<<128, H, 0, stream>>>(Wa, WaH4);
    dim3 ggrid(T * B / 64, G4 / 64);
    gemm_g<<<ggrid, 256, 0, stream>>>(embs, Wih, bih, bhh, G);
    alstm8<<<B / NB, 1024, 0, stream>>>(lens, G, WhH4, WaH4, ba, out);
}

// Round 14
// 2033.585 us; speedup vs baseline: 1.1239x; 1.1239x over previous
//
#include <hip/hip_runtime.h>
#include <math.h>

#define T 128
#define B 128
#define H 256
#define I 256
#define G4 1024  // 4*H
#define NB 2     // batch elements per block

typedef unsigned short u16;
typedef unsigned int u32;
typedef _Float16 half_t;
typedef _Float16 half2_t __attribute__((ext_vector_type(2)));

#if defined(__has_builtin)
#if __has_builtin(__builtin_amdgcn_fdot2)
#define HAS_FDOT2 1
#endif
#endif

__device__ __forceinline__ float fdot2(half2_t a, half2_t b, float c) {
#ifdef HAS_FDOT2
    return __builtin_amdgcn_fdot2(a, b, c, false);
#else
    return fmaf((float)a.x, (float)b.x, fmaf((float)a.y, (float)b.y, c));
#endif
}
__device__ __forceinline__ half2_t h2cast(u32 u) { return __builtin_bit_cast(half2_t, u); }

__device__ __forceinline__ float sigmoid_fast(float x) {
    return 1.0f / (1.0f + __expf(-x));
}
__device__ __forceinline__ float tanh_fast(float x) {
    x = fminf(fmaxf(x, -15.f), 15.f);
    const float e = __expf(2.0f * x);
    return (e - 1.0f) / (e + 1.0f);
}

// LDS-only barrier (validated rounds 9-13: bit-identical absmax, neutral cost).
#define BARL() do {                                        \
    asm volatile("s_waitcnt lgkmcnt(0)" ::: "memory");     \
    __builtin_amdgcn_s_barrier();                          \
} while (0)

// ---------------- weight repack (one-shot, fp16 k-pair-major == coalesced) ----------------
// WhH[k2][o] = half2{Whh[o][2k2], Whh[o][2k2+1]},  k2<128, o<1024  (proven alstm7 layout)
__global__ void pack_whH(const float* __restrict__ Whh, half2_t* __restrict__ WhH) {
    const int k2 = blockIdx.x;      // 0..127
    const int o  = threadIdx.x;     // 0..1023
    half2_t v;
    v.x = (half_t)Whh[(size_t)o * H + 2 * k2];
    v.y = (half_t)Whh[(size_t)o * H + 2 * k2 + 1];
    WhH[(size_t)k2 * G4 + o] = v;
}
// WaH[k2][j] = half2{Wa[j][2k2], Wa[j][2k2+1]},  k2<256, j<256
__global__ void pack_waH(const float* __restrict__ Wa, half2_t* __restrict__ WaH) {
    const int k2 = blockIdx.x;      // 0..255
    const int j  = threadIdx.x;     // 0..255
    half2_t v;
    v.x = (half_t)Wa[(size_t)j * (2 * H) + 2 * k2];
    v.y = (half_t)Wa[(size_t)j * (2 * H) + 2 * k2 + 1];
    WaH[(size_t)k2 * H + j] = v;
}

// ---------------- G = embs @ Wih^T + bih + bhh ----------------
__global__ __launch_bounds__(256) void gemm_g(const float* __restrict__ A,
                                              const float* __restrict__ W,
                                              const float* __restrict__ bih,
                                              const float* __restrict__ bhh,
                                              float* __restrict__ G) {
    __shared__ __align__(16) float As[64][68];
    __shared__ __align__(16) float Ws[64][68];
    const int m0 = blockIdx.x * 64;
    const int n0 = blockIdx.y * 64;
    const int tid = threadIdx.x;
    const int ty = tid >> 4, tx = tid & 15;
    const int rr = tid >> 4;
    const int kr = tid & 15;

    float acc[4][4] = {};
    for (int k0 = 0; k0 < I; k0 += 64) {
#pragma unroll
        for (int i = 0; i < 4; ++i) {
            const int r = rr + 16 * i;
            const float4 av = *(const float4*)&A[(size_t)(m0 + r) * I + k0 + kr * 4];
            const float4 wv = *(const float4*)&W[(size_t)(n0 + r) * I + k0 + kr * 4];
            As[kr * 4 + 0][r] = av.x; As[kr * 4 + 1][r] = av.y;
            As[kr * 4 + 2][r] = av.z; As[kr * 4 + 3][r] = av.w;
            Ws[kr * 4 + 0][r] = wv.x; Ws[kr * 4 + 1][r] = wv.y;
            Ws[kr * 4 + 2][r] = wv.z; Ws[kr * 4 + 3][r] = wv.w;
        }
        __syncthreads();
#pragma unroll 8
        for (int kk = 0; kk < 64; ++kk) {
            const float4 a4 = *(const float4*)&As[kk][ty * 4];
            const float4 w4 = *(const float4*)&Ws[kk][tx * 4];
            const float a[4] = {a4.x, a4.y, a4.z, a4.w};
            const float w[4] = {w4.x, w4.y, w4.z, w4.w};
#pragma unroll
            for (int i = 0; i < 4; ++i)
#pragma unroll
                for (int jj = 0; jj < 4; ++jj)
                    acc[i][jj] = fmaf(a[i], w[jj], acc[i][jj]);
        }
        __syncthreads();
    }
    const int n = n0 + tx * 4;
    const float4 bi = *(const float4*)&bih[n];
    const float4 bh = *(const float4*)&bhh[n];
    const float4 bb = make_float4(bi.x + bh.x, bi.y + bh.y, bi.z + bh.z, bi.w + bh.w);
#pragma unroll
    for (int i = 0; i < 4; ++i) {
        const int m = m0 + ty * 4 + i;
        float4 o = make_float4(acc[i][0] + bb.x, acc[i][1] + bb.y,
                               acc[i][2] + bb.z, acc[i][3] + bb.w);
        *(float4*)&G[(size_t)m * G4 + n] = o;
    }
}

// ---------------- recurrent attention-LSTM: alstm7 streams + restructured phases ----------------
// Phases/step (7 BARLs): scores | redundant-softmax+ctx-partials+Gstash |
//   ctx-reduce(512) ∥ Wa·h GEMV(512) | Wa·ctx GEMV(512) | hin-reduce |
//   Whh GEMV(1024) | cell(512)
// LDS: hid 131072 + sc 1024 + hH 1024 + hcI 2048 + hinI 1024 + red 8192
//      + wa_red 8192 + gate 8192 + invs 8 = 160776 <= 163840 (1 block/CU, 16 waves)
__global__ __launch_bounds__(1024, 4) void alstm9(
    const int* __restrict__ lens,
    const float* __restrict__ G,       // [T*B][4H]
    const half2_t* __restrict__ WhH,   // [128][1024] k2-major
    const half2_t* __restrict__ WaH,   // [256][256]  k2-major
    const float* __restrict__ ba,
    float* __restrict__ out)           // hs | h_fin | c_fin
{
    __shared__ __align__(16) half_t hid_s[NB][T][H];   // fp16 history, 128 KB
    __shared__ __align__(16) float  sc_s[NB][T];       // RAW scores
    __shared__ __align__(16) half_t hH_s[NB][H];       // h (for scores)
    __shared__ __align__(16) half_t hcI_s[4 * 256];    // [h|ctx], batch-interleaved k-pairs
    __shared__ __align__(16) half_t hinI_s[4 * 128];   // hin, batch-interleaved k-pairs
    __shared__ __align__(16) float  red_s[2048];       // ctx partials / Whh outputs
    __shared__ __align__(16) float  wa_red[2048];      // Wa partials (4 chunks x 2 batches x 256)
    __shared__ __align__(16) float  gate_s[NB][G4];    // prefetched G rows
    __shared__            float  invs_s[2];            // 1/softmax-sum per batch

    const int b0 = blockIdx.x * NB;
    const int tid = threadIdx.x;
    const int lane = tid & 63;
    const int wave = tid >> 6;        // 0..15
    const int sb = wave >> 3;         // scores batch
    const int stp0 = wave & 7;        // scores t'-stride id
    const int cb = tid >> 9;          // ctx/softmax batch (uniform per wave)
    const int ck = (tid >> 8) & 1;    // ctx 2-way t-split
    const int cj = tid & 255;         // ctx feature
    const int aj = tid & 255;         // Wa output j
    const int akoh = (tid >> 8) - 2;  // Wa h-half chunk {0,1} for tid>=512
    const int akoc = (tid >> 8) + 2;  // Wa ctx-half chunk {2,3} for tid<512
    const int eb = tid >> 8;          // cell batch (valid under tid<512)
    const int ej = tid & 255;         // cell feature

    const int len0 = lens[b0], len1 = lens[b0 + 1];
    float c_reg = 0.f;
    float* hfin = out + (size_t)T * B * H;
    float* cfin = hfin + (size_t)B * H;
    if (tid < 512) hH_s[eb][ej] = (half_t)0.f;

    // Coalesced weight streams (alstm7-proven layout)
    const half2_t* wph = (tid >= 512) ? &WaH[(size_t)(akoh * 64) * H + aj] : WaH;  // h-half
    const half2_t* wpc = (tid < 512)  ? &WaH[(size_t)(akoc * 64) * H + aj] : WaH;  // ctx-half
    const half2_t* whp = &WhH[tid];
    BARL();

    for (int t = 0; t < T; ++t) {
        // G-row loads issue here; consumed at the gate stash (P1).
        const float gA = G[((size_t)t * B + b0) * G4 + tid];
        const float gB = G[((size_t)t * B + b0 + 1) * G4 + tid];

        if (t > 0) {
            // ---- P0: scores -> RAW sc_s (8 waves per batch, t' strided) ----
            {
                const half2_t h2a = h2cast(*(const u32*)&hH_s[sb][lane * 4]);
                const half2_t h2b = h2cast(*(const u32*)&hH_s[sb][lane * 4 + 2]);
                for (int tp = stp0; tp < t; tp += 8) {
                    const uint2 hv = *(const uint2*)&hid_s[sb][tp][lane * 4];
                    float d = fdot2(h2cast(hv.x), h2a, fdot2(h2cast(hv.y), h2b, 0.f));
#pragma unroll
                    for (int off = 32; off; off >>= 1) d += __shfl_xor(d, off);
                    if (lane == 0) sc_s[sb][tp] = d;
                }
            }
            BARL();  // A
            // ---- P1: redundant per-wave softmax + ctx partials (unnormalized) + G stash ----
            {
                const float v0 = (lane < t) ? sc_s[cb][lane] : -3.0e38f;
                const float v1 = (lane + 64 < t) ? sc_s[cb][lane + 64] : -3.0e38f;
                float m = fmaxf(v0, v1);
#pragma unroll
                for (int off = 32; off; off >>= 1) m = fmaxf(m, __shfl_xor(m, off));
                float s = ((lane < t) ? __expf(v0 - m) : 0.f)
                        + ((lane + 64 < t) ? __expf(v1 - m) : 0.f);
#pragma unroll
                for (int off = 32; off; off >>= 1) s += __shfl_xor(s, off);
                if (lane == 0 && (wave == 0 || wave == 8)) invs_s[cb] = 1.f / s;
                float cacc = 0.f;
                for (int tp = ck; tp < t; tp += 2) {
                    const float e = __expf(sc_s[cb][tp] - m);
                    cacc = fmaf(e, (float)hid_s[cb][tp][cj], cacc);
                }
                red_s[cb * 512 + ck * 256 + cj] = cacc;
                gate_s[0][tid] = gA;
                gate_s[1][tid] = gB;
            }
            BARL();  // B
            // ---- P2: ctx reduce+normalize (tid<512)  ∥  Wa·h-half GEMV (tid>=512) ----
            if (tid < 512) {
                const float invs = invs_s[eb];
                const float ctxv = (red_s[eb * 512 + ej] + red_s[eb * 512 + 256 + ej]) * invs;
                hcI_s[512 + 4 * (ej >> 1) + 2 * eb + (ej & 1)] = (half_t)ctxv;
            } else {
                float a0 = 0.f, a1 = 0.f;
#pragma unroll 8
                for (int kk = 0; kk < 64; ++kk) {
                    const int k2 = akoh * 64 + kk;           // k2 < 128 -> h half
                    const uint2 hh = *(const uint2*)&hcI_s[4 * k2];
                    const half2_t w = wph[(size_t)kk * H];
                    a0 = fdot2(w, h2cast(hh.x), a0);
                    a1 = fdot2(w, h2cast(hh.y), a1);
                }
                wa_red[akoh * 512 + aj] = a0;
                wa_red[akoh * 512 + 256 + aj] = a1;
            }
            BARL();  // C
            // ---- P3: Wa·ctx-half GEMV (tid<512) ----
            if (tid < 512) {
                float a0 = 0.f, a1 = 0.f;
#pragma unroll 8
                for (int kk = 0; kk < 64; ++kk) {
                    const int k2 = akoc * 64 + kk;           // k2 in [128,256) -> ctx half
                    const uint2 hh = *(const uint2*)&hcI_s[4 * k2];
                    const half2_t w = wpc[(size_t)kk * H];
                    a0 = fdot2(w, h2cast(hh.x), a0);
                    a1 = fdot2(w, h2cast(hh.y), a1);
                }
                wa_red[akoc * 512 + aj] = a0;
                wa_red[akoc * 512 + 256 + aj] = a1;
            }
            BARL();  // D
            // ---- P4: hin reduce + tanh ----
            if (tid < 512) {
                float a = ba[ej];
#pragma unroll
                for (int r = 0; r < 4; ++r) a += wa_red[r * 512 + eb * 256 + ej];
                hinI_s[4 * (ej >> 1) + 2 * eb + (ej & 1)] = (half_t)tanh_fast(a);
            }
            BARL();  // E
            // ---- P5: Whh GEMV (one output o=tid, both batches, alstm7 stream) ----
            {
                float g0 = 0.f, g1 = 0.f;
#pragma unroll 8
                for (int k2 = 0; k2 < 128; ++k2) {
                    const uint2 hh = *(const uint2*)&hinI_s[4 * k2];
                    const half2_t w = whp[(size_t)k2 * G4];
                    g0 = fdot2(w, h2cast(hh.x), g0);
                    g1 = fdot2(w, h2cast(hh.y), g1);
                }
                red_s[tid] = g0;
                red_s[1024 + tid] = g1;
            }
        } else {
            // t == 0: h_in = 0 -> recurrent contribution is exactly 0
            gate_s[0][tid] = gA;
            gate_s[1][tid] = gB;
            red_s[tid] = 0.f;
            red_s[1024 + tid] = 0.f;
        }
        BARL();  // F
        // ---- P6: gate sum + cell update (threads 0..511) ----
        if (tid < 512) {
            const int bg = b0 + eb;
            const float gi = gate_s[eb][ej]         + red_s[eb * 1024 + ej];
            const float gf = gate_s[eb][H + ej]     + red_s[eb * 1024 + H + ej];
            const float gg = gate_s[eb][2 * H + ej] + red_s[eb * 1024 + 2 * H + ej];
            const float go = gate_s[eb][3 * H + ej] + red_s[eb * 1024 + 3 * H + ej];
            const float ig = sigmoid_fast(gi);
            const float fg = sigmoid_fast(gf);
            const float gv = tanh_fast(gg);
            const float og = sigmoid_fast(go);
            c_reg = fmaf(fg, c_reg, ig * gv);
            const float h_new = og * tanh_fast(c_reg);
            const half_t hh = (half_t)h_new;
            hH_s[eb][ej] = hh;
            hid_s[eb][t][ej] = hh;
            hcI_s[4 * (ej >> 1) + 2 * eb + (ej & 1)] = hh;
            out[((size_t)t * B + bg) * H + ej] = h_new;
            const int lb = eb ? len1 : len0;
            if (t == lb - 1) {
                hfin[(size_t)bg * H + ej] = h_new;
                cfin[(size_t)bg * H + ej] = c_reg;
            }
        }
        BARL();  // G
    }
}

extern "C" void kernel_launch(void* const* d_in, const int* in_sizes, int n_in,
                              void* d_out, int out_size, void* d_ws, size_t ws_size,
                              hipStream_t stream) {
    const float* embs = (const float*)d_in[0];
    const int*   lens = (const int*)d_in[1];
    const float* Wih  = (const float*)d_in[2];
    const float* Whh  = (const float*)d_in[3];
    const float* bih  = (const float*)d_in[4];
    const float* bhh  = (const float*)d_in[5];
    const float* Wa   = (const float*)d_in[6];
    const float* ba   = (const float*)d_in[7];
    float* out = (float*)d_out;

    // ws layout: G fp32 [T*B][4H] (64 MB) | WhH half2[128*1024] (512 KB) | WaH half2[256*256] (256 KB)
    float* G      = (float*)d_ws;
    half2_t* WhH  = (half2_t*)(G + (size_t)T * B * G4);
    half2_t* WaH  = WhH + (size_t)128 * G4;

    pack_whH<<<128, G4, 0, stream>>>(Whh, WhH);
    pack_waH<<<256, H, 0, stream>>>(Wa, WaH);
    dim3 ggrid(T * B / 64, G4 / 64);
    gemm_g<<<ggrid, 256, 0, stream>>>(embs, Wih, bih, bhh, G);
    alstm9<<<B / NB, 1024, 0, stream>>>(lens, G, WhH, WaH, ba, out);
}